// Round 1
// 223.855 us; speedup vs baseline: 1.0819x; 1.0819x over previous
//
#include <hip/hip_runtime.h>

// Problem constants:
//   vol [B=2, C=16, D=96, H=96, W=96] f32
//   xyz_sample [2, 512, 3] f32
//   A [1024, 3, 3] f32
//   weight [6, 1024] f32
//   out [2, 16*512, 1024] f32  (flat: b*8388608 + (c*512+f)*1024 + k)

#define NB 2
#define NC 16
#define NS 96
#define FEATS 512
#define NK 1024
#define KSPLIT 4
#define KSHIFT 2
#define KCHUNK (NK / KSPLIT)   // 256
#define DPASSES (KCHUNK / 128) // 2 passes, 128 k-slots x 2 lanes (duo)

#define RVOX 8        // staged region extent per axis (voxels)
#define VSTRIDE 48    // LDS bytes per voxel: 32 payload + 16 pad (16B-aligned, bank-spread)

#define TP 388   // transpose LDS row stride (floats): %4==0 (b128-aligned), %32==4 (2-way only)

// ---------------------------------------------------------------------------
// Transpose + downconvert: [B,C,D,H,W] f32 -> [B,D,H,W,C] bf16.
// One block per (b, d, hq): 4 h-rows. float4 loads, b128 LDS, uint4 stores.
// ---------------------------------------------------------------------------
__device__ __forceinline__ unsigned int bfround(float f) {
  unsigned int u = __float_as_uint(f);
  return (u + 0x7fffu + ((u >> 16) & 1u)) >> 16;  // RNE
}

__global__ __launch_bounds__(256) void transpose_bf16_kernel(
    const float* __restrict__ vol, unsigned short* __restrict__ volT) {
  int bid = blockIdx.x;            // b*96*24 + d*24 + hq
  int hq = bid % 24;
  int t = bid / 24;
  int d = t % NS;
  int b = t / NS;

  __shared__ float sm[NC * TP];    // 24.8 KB
  int tid = threadIdx.x;

  // Load: 6 float4/thread, contiguous over the (h,w) plane per channel.
  const float4* v4 = (const float4*)vol;
#pragma unroll
  for (int j = 0; j < 6; j++) {
    int i = tid + 256 * j;         // 0..1535
    int c = i / 96;
    int u = i - c * 96;            // float4 index within the 4-row chunk
    size_t src = (size_t)((b * NC + c) * NS + d) * 2304 + hq * 96 + u;
    *(float4*)&sm[c * TP + u * 4] = v4[src];
  }
  __syncthreads();

  // Store: 3 x 16B chunks/thread. Chunk m: t16 = h_local*96+w, ch = c-half.
  size_t dstb = ((size_t)(b * NS + d) * 9216 + (size_t)hq * 384) * NC;  // ushort idx
#pragma unroll
  for (int j = 0; j < 3; j++) {
    int m = tid + 256 * j;         // 0..767
    int t16 = m >> 1;
    int ch = m & 1;
    unsigned int r[4];
#pragma unroll
    for (int q = 0; q < 4; q++) {
      float lo = sm[(ch * 8 + 2 * q) * TP + t16];
      float hi = sm[(ch * 8 + 2 * q + 1) * TP + t16];
      r[q] = bfround(lo) | (bfround(hi) << 16);
    }
    *(uint4*)(volT + dstb + (size_t)m * 8) = make_uint4(r[0], r[1], r[2], r[3]);
  }
}

// ---------------------------------------------------------------------------
// bf16 unpack helpers
// ---------------------------------------------------------------------------
#define BLO(v) __uint_as_float((v) << 16)
#define BHI(v) __uint_as_float((v) & 0xffff0000u)

// ---------------------------------------------------------------------------
// Duo-split trilinear. Each lane owns 8 channels (uint4 = 16B per corner);
// 2 lanes cover a sample. Fast path: corners read from the LDS-staged 8^3
// neighborhood (zero-padded => no bounds checks). Slow path (rare, >6-sigma
// offsets): global gather with volume-OOB checks.
// ---------------------------------------------------------------------------
__device__ __forceinline__ void tri_duo(
    const unsigned short* __restrict__ vg,   // volT + duo*8
    size_t bbase,
    const unsigned char* __restrict__ sp,    // staged LDS base + duo*16
    int ox0, int oy0, int oz0,
    float x, float y, float z, float sgn, float acc[8]) {
  float fx0 = floorf(x), fy0 = floorf(y), fz0 = floorf(z);
  int ix0 = (int)fx0, iy0 = (int)fy0, iz0 = (int)fz0;
  float tx = x - fx0, ty = y - fy0, tz = z - fz0;
  float wxa[2] = {1.0f - tx, tx};
  float wya[2] = {1.0f - ty, ty};
  float wza[2] = {1.0f - tz, tz};

  int lx0 = ix0 - ox0, ly0 = iy0 - oy0, lz0 = iz0 - oz0;
  bool fast = ((unsigned)lx0 < 7u) & ((unsigned)ly0 < 7u) & ((unsigned)lz0 < 7u);

  if (__builtin_expect(fast, 1)) {
#pragma unroll
    for (int dz = 0; dz < 2; dz++) {
      float wz = sgn * wza[dz];
#pragma unroll
      for (int dy = 0; dy < 2; dy++) {
        float wzy = wz * wya[dy];
        const unsigned char* rp =
            sp + (((lz0 + dz) * RVOX + (ly0 + dy)) * RVOX + lx0) * VSTRIDE;
#pragma unroll
        for (int dx = 0; dx < 2; dx++) {
          float w = wzy * wxa[dx];
          uint4 u = *(const uint4*)(rp + dx * VSTRIDE);
          acc[0] += w * BLO(u.x);
          acc[1] += w * BHI(u.x);
          acc[2] += w * BLO(u.y);
          acc[3] += w * BHI(u.y);
          acc[4] += w * BLO(u.z);
          acc[5] += w * BHI(u.z);
          acc[6] += w * BLO(u.w);
          acc[7] += w * BHI(u.w);
        }
      }
    }
  } else {
#pragma unroll
    for (int dz = 0; dz < 2; dz++) {
      int zc = iz0 + dz;
      if ((unsigned)zc >= (unsigned)NS) continue;
#pragma unroll
      for (int dy = 0; dy < 2; dy++) {
        int yc = iy0 + dy;
        if ((unsigned)yc >= (unsigned)NS) continue;
        size_t rowb = bbase + ((size_t)zc * NS + yc) * (NS * NC);
        float wzy = sgn * wza[dz] * wya[dy];
#pragma unroll
        for (int dx = 0; dx < 2; dx++) {
          int xc = ix0 + dx;
          if ((unsigned)xc >= (unsigned)NS) continue;
          float w = wzy * wxa[dx];
          uint4 u = *(const uint4*)(vg + rowb + (size_t)xc * NC);
          acc[0] += w * BLO(u.x);
          acc[1] += w * BHI(u.x);
          acc[2] += w * BLO(u.y);
          acc[3] += w * BHI(u.y);
          acc[4] += w * BLO(u.z);
          acc[5] += w * BHI(u.z);
          acc[6] += w * BLO(u.w);
          acc[7] += w * BHI(u.w);
        }
      }
    }
  }
}

// ---------------------------------------------------------------------------
// Sample kernel: one block per (b, f, kseg). All 2048 gather points of a
// block cluster within ~±2 voxels of one base point, so stage the 8^3
// neighborhood (zero-padded) in LDS once, then gather via ds_read_b128.
// ---------------------------------------------------------------------------
__global__ __launch_bounds__(256) void sample_kernel_q(
    const unsigned short* __restrict__ volT,  // [B,D,H,W,C] bf16
    const float* __restrict__ xyz, const float* __restrict__ A,
    const float* __restrict__ weight, float* __restrict__ out) {
  __shared__ float wsm[6 * KCHUNK];                                   // 6 KB
  __shared__ __align__(16) unsigned char stage[RVOX * RVOX * RVOX * VSTRIDE];  // 24.5 KB

  int bid = blockIdx.x;
  int kseg = bid & (KSPLIT - 1);
  int n = bid >> KSHIFT;                // b*512 + f
  int b = n >> 9;
  int f = n & 511;
  int kbase = kseg * KCHUNK;

  for (int i = threadIdx.x; i < 6 * KCHUNK; i += 256)
    wsm[i] = weight[(i / KCHUNK) * NK + kbase + (i % KCHUNK)];

  const float* An = A + (size_t)n * 9;
  float a00 = An[0], a01 = An[1], a02 = An[2];
  float a10 = An[3], a11 = An[4], a12 = An[5];
  float a20 = An[6], a21 = An[7], a22 = An[8];
  const float* Xn = xyz + (size_t)n * 3;
  float bx = (Xn[0] + 1.0f) * 48.0f - 0.5f;  // W axis <- xs[0]
  float by = (Xn[1] + 1.0f) * 48.0f - 0.5f;  // H axis <- xs[1]
  float bz = (Xn[2] + 1.0f) * 48.0f - 0.5f;  // D axis <- xs[2]

  // Staged region origin (block-uniform): [floor(base)-3, floor(base)+4].
  int ox0 = (int)floorf(bx) - 3;
  int oy0 = (int)floorf(by) - 3;
  int oz0 = (int)floorf(bz) - 3;

  size_t bbase = (size_t)b * (NS * NS * NS * NC);

  // Stage 512 voxels x 32 B, zero-filling volume-OOB voxels. 2 voxels/thread.
  for (int v = threadIdx.x; v < RVOX * RVOX * RVOX; v += 256) {
    int dx = v & 7, dy = (v >> 3) & 7, dz = v >> 6;
    int xc = ox0 + dx, yc = oy0 + dy, zc = oz0 + dz;
    uint4 lo = make_uint4(0u, 0u, 0u, 0u);
    uint4 hi = make_uint4(0u, 0u, 0u, 0u);
    if (((unsigned)xc < (unsigned)NS) & ((unsigned)yc < (unsigned)NS) &
        ((unsigned)zc < (unsigned)NS)) {
      const uint4* g = (const uint4*)(volT + bbase +
                                      (((size_t)zc * NS + yc) * NS + xc) * NC);
      lo = g[0];
      hi = g[1];
    }
    unsigned char* p = stage + (size_t)v * VSTRIDE;
    *(uint4*)p = lo;
    *(uint4*)(p + 16) = hi;
  }
  __syncthreads();

  int duo = threadIdx.x & 1;            // which 8-channel half
  int ksub = threadIdx.x >> 1;          // 0..127
  const unsigned short* vg = volT + duo * 8;
  const unsigned char* sp = stage + duo * 16;
  size_t obase = (size_t)b * (NC * FEATS * NK) +
                 (size_t)(duo * 8) * (FEATS * NK) + (size_t)f * NK + kbase;

  for (int pass = 0; pass < DPASSES; pass++) {
    int kl = pass * 128 + ksub;
    float w0 = wsm[kl];
    float w1 = wsm[KCHUNK + kl];
    float w2 = wsm[2 * KCHUNK + kl];
    float w3 = wsm[3 * KCHUNK + kl];
    float w4 = wsm[4 * KCHUNK + kl];
    float w5 = wsm[5 * KCHUNK + kl];

    float acc[8] = {0.0f, 0.0f, 0.0f, 0.0f, 0.0f, 0.0f, 0.0f, 0.0f};

    {  // grid 1 (+)
      float oz = a00 * w0 + a01 * w1 + a02 * w2;
      float oy = a10 * w0 + a11 * w1 + a12 * w2;
      float ox = a20 * w0 + a21 * w1 + a22 * w2;
      tri_duo(vg, bbase, sp, ox0, oy0, oz0, bx + ox * 48.0f, by + oy * 48.0f,
              bz + oz * 48.0f, 1.0f, acc);
    }
    {  // grid 2 (-)
      float oz = a00 * w3 + a01 * w4 + a02 * w5;
      float oy = a10 * w3 + a11 * w4 + a12 * w5;
      float ox = a20 * w3 + a21 * w4 + a22 * w5;
      tri_duo(vg, bbase, sp, ox0, oy0, oz0, bx + ox * 48.0f, by + oy * 48.0f,
              bz + oz * 48.0f, -1.0f, acc);
    }

    size_t o = obase + kl;
#pragma unroll
    for (int c = 0; c < 8; c++)
      out[o + (size_t)c * (FEATS * NK)] = acc[c];
  }
}

// ---------------------------------------------------------------------------
// Fallback (no workspace): scalar-gather on original f32 layout.
// ---------------------------------------------------------------------------
__global__ __launch_bounds__(256) void sample_kernel_fallback(
    const float* __restrict__ vol, const float* __restrict__ xyz,
    const float* __restrict__ A, const float* __restrict__ weight,
    float* __restrict__ out) {
  int n = blockIdx.x;
  int b = n >> 9;
  int f = n & 511;
  const float* An = A + (size_t)n * 9;
  float a00 = An[0], a01 = An[1], a02 = An[2];
  float a10 = An[3], a11 = An[4], a12 = An[5];
  float a20 = An[6], a21 = An[7], a22 = An[8];
  const float* Xn = xyz + (size_t)n * 3;
  float bx = (Xn[0] + 1.0f) * 48.0f - 0.5f;
  float by = (Xn[1] + 1.0f) * 48.0f - 0.5f;
  float bz = (Xn[2] + 1.0f) * 48.0f - 0.5f;
  size_t obase = (size_t)b * (NC * FEATS * NK) + (size_t)f * NK;

  for (int k = threadIdx.x; k < NK; k += 256) {
    float w0 = weight[k], w1 = weight[NK + k], w2 = weight[2 * NK + k];
    float w3 = weight[3 * NK + k], w4 = weight[4 * NK + k],
          w5 = weight[5 * NK + k];
    float acc[NC];
#pragma unroll
    for (int c = 0; c < NC; c++) acc[c] = 0.0f;
    for (int g = 0; g < 2; g++) {
      float u0 = g ? w3 : w0, u1 = g ? w4 : w1, u2 = g ? w5 : w2;
      float sgn = g ? -1.0f : 1.0f;
      float oz = a00 * u0 + a01 * u1 + a02 * u2;
      float oy = a10 * u0 + a11 * u1 + a12 * u2;
      float ox = a20 * u0 + a21 * u1 + a22 * u2;
      float x = bx + ox * 48.0f, y = by + oy * 48.0f, z = bz + oz * 48.0f;
      float fx0 = floorf(x), fy0 = floorf(y), fz0 = floorf(z);
      int ix0 = (int)fx0, iy0 = (int)fy0, iz0 = (int)fz0;
      float tx = x - fx0, ty = y - fy0, tz = z - fz0;
      float wxa[2] = {1.0f - tx, tx}, wya[2] = {1.0f - ty, ty},
            wza[2] = {1.0f - tz, tz};
      for (int dz = 0; dz < 2; dz++) {
        int zc = iz0 + dz;
        if ((unsigned)zc >= (unsigned)NS) continue;
        for (int dy = 0; dy < 2; dy++) {
          int yc = iy0 + dy;
          if ((unsigned)yc >= (unsigned)NS) continue;
          for (int dx = 0; dx < 2; dx++) {
            int xc = ix0 + dx;
            if ((unsigned)xc >= (unsigned)NS) continue;
            float w = sgn * wza[dz] * wya[dy] * wxa[dx];
            size_t base = (size_t)b * NC * NS * NS * NS +
                          (size_t)zc * NS * NS + (size_t)yc * NS + xc;
#pragma unroll
            for (int c = 0; c < NC; c++)
              acc[c] += w * vol[base + (size_t)c * (NS * NS * NS)];
          }
        }
      }
    }
#pragma unroll
    for (int c = 0; c < NC; c++)
      out[obase + (size_t)c * (FEATS * NK) + k] = acc[c];
  }
}

extern "C" void kernel_launch(void* const* d_in, const int* in_sizes, int n_in,
                              void* d_out, int out_size, void* d_ws,
                              size_t ws_size, hipStream_t stream) {
  const float* vol    = (const float*)d_in[0];
  const float* xyz    = (const float*)d_in[1];
  const float* A      = (const float*)d_in[2];
  const float* weight = (const float*)d_in[3];
  float* out = (float*)d_out;

  const size_t volT_bytes =
      (size_t)NB * NC * NS * NS * NS * sizeof(unsigned short);

  if (ws_size >= volT_bytes) {
    unsigned short* volT = (unsigned short*)d_ws;
    transpose_bf16_kernel<<<NB * NS * 24, 256, 0, stream>>>(vol, volT);
    sample_kernel_q<<<NB * FEATS * KSPLIT, 256, 0, stream>>>(volT, xyz, A,
                                                             weight, out);
  } else {
    sample_kernel_fallback<<<NB * FEATS, 256, 0, stream>>>(vol, xyz, A, weight,
                                                           out);
  }
}

// Round 3
// 199.962 us; speedup vs baseline: 1.2112x; 1.1195x over previous
//
#include <hip/hip_runtime.h>

// Problem constants:
//   vol [B=2, C=16, D=96, H=96, W=96] f32
//   xyz_sample [2, 512, 3] f32
//   A [1024, 3, 3] f32
//   weight [6, 1024] f32
//   out [2, 16*512, 1024] f32  (flat: b*8388608 + (c*512+f)*1024 + k)

#define NB 2
#define NC 16
#define NS 96
#define NS3 (NS * NS * NS)
#define FEATS 512
#define NK 1024
#define KSPLIT 2
#define KCHUNK (NK / KSPLIT)   // 512
#define PASSES 4               // KCHUNK / 128 (128 k-slots x 2 duo lanes / pass)

#define RVOX 8        // staged region extent per axis (voxels)
#define VSTRIDE 48    // LDS bytes per voxel: 32 payload + 16 pad

__device__ __forceinline__ unsigned int bfround(float f) {
  unsigned int u = __float_as_uint(f);
  return (u + 0x7fffu + ((u >> 16) & 1u)) >> 16;  // RNE, matches prior volT
}

#define BLO(v) __uint_as_float((v) << 16)
#define BHI(v) __uint_as_float((v) & 0xffff0000u)

// ---------------------------------------------------------------------------
// Duo-split trilinear. Each lane owns 8 channels (uint4 = 16B per corner);
// 2 lanes cover a sample. Fast path: LDS-staged 8^3 neighborhood
// (zero-padded => no bounds checks). Slow path (>6-sigma offsets, ~never):
// direct f32 gather from the original [B,C,D,H,W] volume.
// ---------------------------------------------------------------------------
__device__ __forceinline__ void tri_duo(
    const float* __restrict__ vol, size_t cbase,   // vol + (b, duo*8) base
    const unsigned char* __restrict__ sp,          // stage + duo*16
    int ox0, int oy0, int oz0,
    float x, float y, float z, float sgn, float acc[8]) {
  float fx0 = floorf(x), fy0 = floorf(y), fz0 = floorf(z);
  int ix0 = (int)fx0, iy0 = (int)fy0, iz0 = (int)fz0;
  float tx = x - fx0, ty = y - fy0, tz = z - fz0;
  float wxa[2] = {1.0f - tx, tx};
  float wya[2] = {1.0f - ty, ty};
  float wza[2] = {1.0f - tz, tz};

  int lx0 = ix0 - ox0, ly0 = iy0 - oy0, lz0 = iz0 - oz0;
  bool fast = ((unsigned)lx0 < 7u) & ((unsigned)ly0 < 7u) & ((unsigned)lz0 < 7u);

  if (__builtin_expect(fast, 1)) {
#pragma unroll
    for (int dz = 0; dz < 2; dz++) {
      float wz = sgn * wza[dz];
#pragma unroll
      for (int dy = 0; dy < 2; dy++) {
        float wzy = wz * wya[dy];
        const unsigned char* rp =
            sp + (((lz0 + dz) * RVOX + (ly0 + dy)) * RVOX + lx0) * VSTRIDE;
#pragma unroll
        for (int dx = 0; dx < 2; dx++) {
          float w = wzy * wxa[dx];
          uint4 u = *(const uint4*)(rp + dx * VSTRIDE);
          acc[0] += w * BLO(u.x);
          acc[1] += w * BHI(u.x);
          acc[2] += w * BLO(u.y);
          acc[3] += w * BHI(u.y);
          acc[4] += w * BLO(u.z);
          acc[5] += w * BHI(u.z);
          acc[6] += w * BLO(u.w);
          acc[7] += w * BHI(u.w);
        }
      }
    }
  } else {
#pragma unroll
    for (int dz = 0; dz < 2; dz++) {
      int zc = iz0 + dz;
      if ((unsigned)zc >= (unsigned)NS) continue;
#pragma unroll
      for (int dy = 0; dy < 2; dy++) {
        int yc = iy0 + dy;
        if ((unsigned)yc >= (unsigned)NS) continue;
        float wzy = sgn * wza[dz] * wya[dy];
#pragma unroll
        for (int dx = 0; dx < 2; dx++) {
          int xc = ix0 + dx;
          if ((unsigned)xc >= (unsigned)NS) continue;
          float w = wzy * wxa[dx];
          const float* p = vol + cbase + (((size_t)zc * NS + yc) * NS + xc);
#pragma unroll
          for (int c = 0; c < 8; c++)
            acc[c] += w * p[(size_t)c * NS3];
        }
      }
    }
  }
}

// ---------------------------------------------------------------------------
// Fused sample kernel: one block per (b, f, kseg). Stages the 8^3x16ch
// neighborhood directly from the f32 volume (bf16-converted in-register),
// then runs 4 passes of 128 k-slots x 2 duo lanes. No transpose kernel.
// ---------------------------------------------------------------------------
__global__ __launch_bounds__(256) void sample_fused(
    const float* __restrict__ vol, const float* __restrict__ xyz,
    const float* __restrict__ A, const float* __restrict__ weight,
    float* __restrict__ out) {
  __shared__ __align__(16) unsigned char stage[RVOX * RVOX * RVOX * VSTRIDE];  // 24.5 KB

  int bid = blockIdx.x;
  int kseg = bid & (KSPLIT - 1);
  int n = bid >> 1;                     // b*512 + f
  int b = n >> 9;
  int f = n & 511;
  int kbase = kseg * KCHUNK;
  int tid = threadIdx.x;

  const float* Xn = xyz + (size_t)n * 3;
  float bx = (Xn[0] + 1.0f) * 48.0f - 0.5f;  // W axis <- xs[0]
  float by = (Xn[1] + 1.0f) * 48.0f - 0.5f;  // H axis <- xs[1]
  float bz = (Xn[2] + 1.0f) * 48.0f - 0.5f;  // D axis <- xs[2]
  int ox0 = (int)floorf(bx) - 3;
  int oy0 = (int)floorf(by) - 3;
  int oz0 = (int)floorf(bz) - 3;

  int duo = tid & 1;                    // which 8-channel half
  int ksub = tid >> 1;                  // 0..127

  // Preload all per-thread weights into registers; these VMEM loads overlap
  // the staging loads below. (Statically indexed everywhere — rule #20.)
  float wreg[PASSES][6];
#pragma unroll
  for (int p = 0; p < PASSES; p++) {
    int k = kbase + p * 128 + ksub;
#pragma unroll
    for (int q = 0; q < 6; q++) wreg[p][q] = weight[q * NK + k];
  }

  const float* An = A + (size_t)n * 9;
  float a00 = An[0], a01 = An[1], a02 = An[2];
  float a10 = An[3], a11 = An[4], a12 = An[5];
  float a20 = An[6], a21 = An[7], a22 = An[8];

  // Stage 512 voxels x 16ch as bf16, zero-filling volume-OOB voxels.
  // Task w: half = w&1 (8 channels), voxel = w>>1. Lane order keeps the
  // 8-channel scalar loads in ~8 contiguous 32B row-segments per wave-inst,
  // and the ds_write_b128 addresses spread across banks (<=2-way).
  size_t vb = (size_t)b * NC * NS3;
#pragma unroll
  for (int j = 0; j < 4; j++) {
    int w = tid + 256 * j;              // 0..1023
    int half = w & 1;
    int v = w >> 1;                     // voxel 0..511
    int xg = v & 7, yg = (v >> 3) & 7, zg = v >> 6;
    int xc = ox0 + xg, yc = oy0 + yg, zc = oz0 + zg;
    uint4 r = make_uint4(0u, 0u, 0u, 0u);
    if (((unsigned)xc < (unsigned)NS) & ((unsigned)yc < (unsigned)NS) &
        ((unsigned)zc < (unsigned)NS)) {
      const float* p = vol + vb + (size_t)(half * 8) * NS3 +
                       (((size_t)zc * NS + yc) * NS + xc);
      float f0 = p[0];
      float f1 = p[NS3];
      float f2 = p[2 * NS3];
      float f3 = p[3 * NS3];
      float f4 = p[4 * NS3];
      float f5 = p[5 * NS3];
      float f6 = p[6 * NS3];
      float f7 = p[7 * NS3];
      r.x = bfround(f0) | (bfround(f1) << 16);
      r.y = bfround(f2) | (bfround(f3) << 16);
      r.z = bfround(f4) | (bfround(f5) << 16);
      r.w = bfround(f6) | (bfround(f7) << 16);
    }
    *(uint4*)(stage + (size_t)v * VSTRIDE + half * 16) = r;
  }
  __syncthreads();

  const unsigned char* sp = stage + duo * 16;
  size_t cbase = ((size_t)b * NC + duo * 8) * NS3;
  size_t obase = (size_t)b * (NC * FEATS * NK) +
                 (size_t)(duo * 8) * (FEATS * NK) + (size_t)f * NK + kbase;

#pragma unroll
  for (int pass = 0; pass < PASSES; pass++) {
    int kl = pass * 128 + ksub;
    float w0 = wreg[pass][0];
    float w1 = wreg[pass][1];
    float w2 = wreg[pass][2];
    float w3 = wreg[pass][3];
    float w4 = wreg[pass][4];
    float w5 = wreg[pass][5];

    float acc[8] = {0.0f, 0.0f, 0.0f, 0.0f, 0.0f, 0.0f, 0.0f, 0.0f};

    {  // grid 1 (+)
      float oz = a00 * w0 + a01 * w1 + a02 * w2;
      float oy = a10 * w0 + a11 * w1 + a12 * w2;
      float ox = a20 * w0 + a21 * w1 + a22 * w2;
      tri_duo(vol, cbase, sp, ox0, oy0, oz0, bx + ox * 48.0f, by + oy * 48.0f,
              bz + oz * 48.0f, 1.0f, acc);
    }
    {  // grid 2 (-)
      float oz = a00 * w3 + a01 * w4 + a02 * w5;
      float oy = a10 * w3 + a11 * w4 + a12 * w5;
      float ox = a20 * w3 + a21 * w4 + a22 * w5;
      tri_duo(vol, cbase, sp, ox0, oy0, oz0, bx + ox * 48.0f, by + oy * 48.0f,
              bz + oz * 48.0f, -1.0f, acc);
    }

    size_t o = obase + kl;
#pragma unroll
    for (int c = 0; c < 8; c++)
      out[o + (size_t)c * (FEATS * NK)] = acc[c];
  }
}

extern "C" void kernel_launch(void* const* d_in, const int* in_sizes, int n_in,
                              void* d_out, int out_size, void* d_ws,
                              size_t ws_size, hipStream_t stream) {
  const float* vol    = (const float*)d_in[0];
  const float* xyz    = (const float*)d_in[1];
  const float* A      = (const float*)d_in[2];
  const float* weight = (const float*)d_in[3];
  float* out = (float*)d_out;

  sample_fused<<<NB * FEATS * KSPLIT, 256, 0, stream>>>(vol, xyz, A, weight,
                                                        out);
}